// Round 1
// baseline (192.302 us; speedup 1.0000x reference)
//
#include <hip/hip_runtime.h>

#define HH 1024
#define WW 1024
#define NIMG 12

// fwd8: F(l) = sum of a over lanes l..l+7   (valid for lane <= 56)
__device__ __forceinline__ float fwd8(float a) {
  a += __shfl_down(a, 1, 64);
  a += __shfl_down(a, 2, 64);
  a += __shfl_down(a, 4, 64);
  return a;
}
// bwd8: B(l) = sum of a over lanes l-7..l   (valid for lane >= 7)
__device__ __forceinline__ float bwd8(float a) {
  a += __shfl_up(a, 1, 64);
  a += __shfl_up(a, 2, 64);
  a += __shfl_up(a, 4, 64);
  return a;
}

// For global row ry, compute per-lane horizontal windows:
//   lh = sum x[ry][col-7..col],  rh = sum x[ry][col..col+7],  w = x[ry][col]
// Zero padding outside the image. col = strip*64 + lane (always < WW).
__device__ __forceinline__ void hrow(const float* __restrict__ s, int ry, int col, int lane,
                                     float& lh, float& rh, float& w) {
  if ((unsigned)ry < (unsigned)HH) {
    const float* r = s + (size_t)ry * WW;
    float v0 = (col >= 7) ? r[col - 7] : 0.0f;      // x[col-7]
    float v1 = (col + 7 < WW) ? r[col + 7] : 0.0f;  // x[col+7]
    float wc = r[col];                              // x[col]
    // lh: fwd8 on v0 gives sum x[col-7..col] (lanes<=56); bwd8 on wc gives same (lanes>=7)
    float lf = fwd8(v0);
    float lb = bwd8(wc);
    // rh: fwd8 on wc gives sum x[col..col+7] (lanes<=56); bwd8 on v1 gives same (lanes>=7)
    float rf = fwd8(wc);
    float rb = bwd8(v1);
    bool lo = (lane <= 56);
    lh = lo ? lf : lb;
    rh = lo ? rf : rb;
    w  = wc;
  } else {
    lh = 0.0f; rh = 0.0f; w = 0.0f;
  }
}

// One side-window-filter step. Each wave owns a 64-col x 64-row tile and
// streams rows with a 16-deep register ring of (lh, rh, w) rows.
__global__ __launch_bounds__(256) void swf_step(const float* __restrict__ src,
                                                float* __restrict__ dst) {
  const int lane = threadIdx.x & 63;
  const int wid  = threadIdx.x >> 6;
  const int col  = blockIdx.x * 64 + lane;             // 16 strips x 64
  const int y0   = (blockIdx.y * 4 + wid) * 64;        // 16 chunks x 64 rows
  const float* s = src + (size_t)blockIdx.z * HH * WW;
  float* d       = dst + (size_t)blockIdx.z * HH * WW;

  float rlh[16], rrh[16], rw[16];
  // Prologue: rows y0-7 .. y0+6 into slot (row & 15). y0 % 16 == 0 so slot = (j+9)&15.
  #pragma unroll
  for (int j = 0; j < 14; ++j) {
    const int slot = (j + 9) & 15;
    hrow(s, y0 - 7 + j, col, lane, rlh[slot], rrh[slot], rw[slot]);
  }

  #pragma unroll 1
  for (int yb = 0; yb < 64; yb += 16) {
    #pragma unroll
    for (int i = 0; i < 16; ++i) {
      const int y = y0 + yb + i;
      // bring in row y+7 (slot (i+7)&15, evicts row y-9)
      const int ls = (i + 7) & 15;
      hrow(s, y + 7, col, lane, rlh[ls], rrh[ls], rw[ls]);

      // vertical 8-windows: u* over rows y-7..y, d* over rows y..y+7
      float ua = 0.f, ub = 0.f, uc = 0.f, da = 0.f, db = 0.f, dc = 0.f;
      #pragma unroll
      for (int dy = -7; dy <= 0; ++dy) {
        const int sl = (i + dy + 16) & 15;
        ua += rlh[sl]; ub += rrh[sl]; uc += rw[sl];
      }
      #pragma unroll
      for (int dy = 0; dy <= 7; ++dy) {
        const int sl = (i + dy) & 15;
        da += rlh[sl]; db += rrh[sl]; dc += rw[sl];
      }
      const float lh0 = rlh[i], rh0 = rrh[i], w0 = rw[i];

      const float ih = 1.0f / 120.0f, iq = 1.0f / 64.0f;
      const float Ls = ua + da - lh0;   // full 15 rows, left cols
      const float Rs = ub + db - rh0;
      const float Us = ua + ub - uc;    // up 8 rows, full 15 cols
      const float Ds = da + db - dc;
      float d0 = Ls * ih - w0;   // L
      float d1 = Rs * ih - w0;   // R
      float d2 = Us * ih - w0;   // U
      float d3 = Ds * ih - w0;   // D
      float d4 = ua * iq - w0;   // NW
      float d5 = ub * iq - w0;   // NE
      float d6 = da * iq - w0;   // SW
      float d7 = db * iq - w0;   // SE

      // argmin over |d|, first index wins (strict <), matching jnp.argmin
      float bd = d0, ba = fabsf(d0);
      { float a1 = fabsf(d1); if (a1 < ba) { ba = a1; bd = d1; } }
      { float a1 = fabsf(d2); if (a1 < ba) { ba = a1; bd = d2; } }
      { float a1 = fabsf(d3); if (a1 < ba) { ba = a1; bd = d3; } }
      { float a1 = fabsf(d4); if (a1 < ba) { ba = a1; bd = d4; } }
      { float a1 = fabsf(d5); if (a1 < ba) { ba = a1; bd = d5; } }
      { float a1 = fabsf(d6); if (a1 < ba) { ba = a1; bd = d6; } }
      { float a1 = fabsf(d7); if (a1 < ba) { ba = a1; bd = d7; } }

      d[(size_t)y * WW + col] = w0 + bd;
    }
  }
}

extern "C" void kernel_launch(void* const* d_in, const int* in_sizes, int n_in,
                              void* d_out, int out_size, void* d_ws, size_t ws_size,
                              hipStream_t stream) {
  const float* in = (const float*)d_in[0];
  float* out = (float*)d_out;
  float* ws  = (float*)d_ws;   // needs 12*1024*1024*4 = 50.3 MB scratch

  dim3 grid(WW / 64, 4, NIMG);  // 16 col-strips, 4 chunk-groups (x4 waves), 12 planes
  dim3 block(256);

  // iteration = 3 (from setup_inputs), radius = 7 baked in.
  swf_step<<<grid, block, 0, stream>>>(in, out);   // step 1: in  -> out
  swf_step<<<grid, block, 0, stream>>>(out, ws);   // step 2: out -> ws
  swf_step<<<grid, block, 0, stream>>>(ws, out);   // step 3: ws  -> out
}

// Round 2
// 189.710 us; speedup vs baseline: 1.0137x; 1.0137x over previous
//
#include <hip/hip_runtime.h>

#define HH 1024
#define WW 1024
#define NIMG 12

// fwd8: F(l) = sum of a over lanes l..l+7   (valid for lane <= 56)
__device__ __forceinline__ float fwd8(float a) {
  a += __shfl_down(a, 1, 64);
  a += __shfl_down(a, 2, 64);
  a += __shfl_down(a, 4, 64);
  return a;
}
// bwd8: B(l) = sum of a over lanes l-7..l   (valid for lane >= 7)
// NOTE: same balanced pairwise tree as fwd8 over the same 8 values ->
// bitwise-identical result (pair/group order differs only commutatively).
__device__ __forceinline__ float bwd8(float a) {
  a += __shfl_up(a, 1, 64);
  a += __shfl_up(a, 2, 64);
  a += __shfl_up(a, 4, 64);
  return a;
}

// For global row ry, compute per-lane horizontal windows:
//   lh = sum x[ry][col-7..col],  rh = sum x[ry][col..col+7],  w = x[ry][col]
// Zero padding outside the image. col = strip*64 + lane (always < WW).
__device__ __forceinline__ void hrow(const float* __restrict__ s, int ry, int col, int lane,
                                     float& lh, float& rh, float& w) {
  if ((unsigned)ry < (unsigned)HH) {
    const float* r = s + (size_t)ry * WW;
    float v0 = (col >= 7) ? r[col - 7] : 0.0f;      // x[col-7]
    float v1 = (col + 7 < WW) ? r[col + 7] : 0.0f;  // x[col+7]
    float wc = r[col];                              // x[col]
    // lh: fwd8(v0) = sum x[col-7..col] (lanes<=56); bwd8(wc) same (lanes>=7)
    float lf = fwd8(v0);
    float lb = bwd8(wc);
    bool lo = (lane <= 56);
    lh = lo ? lf : lb;
    // rh[col] = lh[col+7]: for lanes<=56 pull from lane+7 (bitwise == fwd8(wc));
    // lanes>=57 need cross-strip data: bwd8(v1) = sum x[col..col+7].
    float rsh = __shfl_down(lh, 7, 64);
    float rb  = bwd8(v1);
    rh = lo ? rsh : rb;
    w  = wc;
  } else {
    lh = 0.0f; rh = 0.0f; w = 0.0f;
  }
}

// One side-window-filter step. Each wave owns a 64-col x 32-row tile and
// streams rows with a 16-deep register ring of (lh, rh, w) rows.
__global__ __launch_bounds__(256) void swf_step(const float* __restrict__ src,
                                                float* __restrict__ dst) {
  const int lane = threadIdx.x & 63;
  const int wid  = threadIdx.x >> 6;
  const int col  = blockIdx.x * 64 + lane;             // 16 strips x 64
  const int y0   = (blockIdx.y * 4 + wid) * 32;        // 32 chunks x 32 rows
  const float* s = src + (size_t)blockIdx.z * HH * WW;
  float* d       = dst + (size_t)blockIdx.z * HH * WW;

  float rlh[16], rrh[16], rw[16];
  // Prologue: rows y0-7 .. y0+6 into slot (row & 15). y0 % 16 == 0 so slot = (j+9)&15.
  #pragma unroll
  for (int j = 0; j < 14; ++j) {
    const int slot = (j + 9) & 15;
    hrow(s, y0 - 7 + j, col, lane, rlh[slot], rrh[slot], rw[slot]);
  }

  #pragma unroll 1
  for (int yb = 0; yb < 32; yb += 16) {
    #pragma unroll
    for (int i = 0; i < 16; ++i) {
      const int y = y0 + yb + i;
      // bring in row y+7 (slot (i+7)&15, evicts row y-9)
      const int ls = (i + 7) & 15;
      hrow(s, y + 7, col, lane, rlh[ls], rrh[ls], rw[ls]);

      // vertical 8-windows: u* over rows y-7..y, d* over rows y..y+7
      float ua = 0.f, ub = 0.f, uc = 0.f, da = 0.f, db = 0.f, dc = 0.f;
      #pragma unroll
      for (int dy = -7; dy <= 0; ++dy) {
        const int sl = (i + dy + 16) & 15;
        ua += rlh[sl]; ub += rrh[sl]; uc += rw[sl];
      }
      #pragma unroll
      for (int dy = 0; dy <= 7; ++dy) {
        const int sl = (i + dy) & 15;
        da += rlh[sl]; db += rrh[sl]; dc += rw[sl];
      }
      const float lh0 = rlh[i], rh0 = rrh[i], w0 = rw[i];

      const float ih = 1.0f / 120.0f, iq = 1.0f / 64.0f;
      const float Ls = ua + da - lh0;   // full 15 rows, left cols
      const float Rs = ub + db - rh0;
      const float Us = ua + ub - uc;    // up 8 rows, full 15 cols
      const float Ds = da + db - dc;
      float d0 = Ls * ih - w0;   // L
      float d1 = Rs * ih - w0;   // R
      float d2 = Us * ih - w0;   // U
      float d3 = Ds * ih - w0;   // D
      float d4 = ua * iq - w0;   // NW
      float d5 = ub * iq - w0;   // NE
      float d6 = da * iq - w0;   // SW
      float d7 = db * iq - w0;   // SE

      // argmin over |d|, first index wins (strict <), matching jnp.argmin
      float bd = d0, ba = fabsf(d0);
      { float a1 = fabsf(d1); if (a1 < ba) { ba = a1; bd = d1; } }
      { float a1 = fabsf(d2); if (a1 < ba) { ba = a1; bd = d2; } }
      { float a1 = fabsf(d3); if (a1 < ba) { ba = a1; bd = d3; } }
      { float a1 = fabsf(d4); if (a1 < ba) { ba = a1; bd = d4; } }
      { float a1 = fabsf(d5); if (a1 < ba) { ba = a1; bd = d5; } }
      { float a1 = fabsf(d6); if (a1 < ba) { ba = a1; bd = d6; } }
      { float a1 = fabsf(d7); if (a1 < ba) { ba = a1; bd = d7; } }

      d[(size_t)y * WW + col] = w0 + bd;
    }
  }
}

extern "C" void kernel_launch(void* const* d_in, const int* in_sizes, int n_in,
                              void* d_out, int out_size, void* d_ws, size_t ws_size,
                              hipStream_t stream) {
  const float* in = (const float*)d_in[0];
  float* out = (float*)d_out;
  float* ws  = (float*)d_ws;   // needs 12*1024*1024*4 = 50.3 MB scratch

  dim3 grid(WW / 64, 8, NIMG);  // 16 col-strips, 8 chunk-groups (x4 waves x 32 rows), 12 planes
  dim3 block(256);

  // iteration = 3 (from setup_inputs), radius = 7 baked in.
  swf_step<<<grid, block, 0, stream>>>(in, out);   // step 1: in  -> out
  swf_step<<<grid, block, 0, stream>>>(out, ws);   // step 2: out -> ws
  swf_step<<<grid, block, 0, stream>>>(ws, out);   // step 3: ws  -> out
}

// Round 6
// 153.897 us; speedup vs baseline: 1.2495x; 1.2327x over previous
//
#include <hip/hip_runtime.h>

#define HH 1024
#define WW 1024
#define NIMG 12

// fwd8: F(l) = sum of a over lanes l..l+7   (valid for lane <= 56)
__device__ __forceinline__ float fwd8(float a) {
  a += __shfl_down(a, 1, 64);
  a += __shfl_down(a, 2, 64);
  a += __shfl_down(a, 4, 64);
  return a;
}
// bwd8: B(l) = sum of a over lanes l-7..l (valid for lane >= 7); same balanced
// pairwise tree as fwd8 over the same 8 values -> bitwise-identical result.
__device__ __forceinline__ float bwd8(float a) {
  a += __shfl_up(a, 1, 64);
  a += __shfl_up(a, 2, 64);
  a += __shfl_up(a, 4, 64);
  return a;
}

struct RowLd { float v0, v1, wc; };

// Issue the 3 global loads for row ry (zero padded outside image).
__device__ __forceinline__ RowLd row_load(const float* __restrict__ s, int ry, int col) {
  RowLd t;
  if ((unsigned)ry < (unsigned)HH) {
    const float* r = s + (size_t)ry * WW;
    t.v0 = (col >= 7) ? r[col - 7] : 0.0f;      // x[col-7]
    t.v1 = (col + 7 < WW) ? r[col + 7] : 0.0f;  // x[col+7]
    t.wc = r[col];                              // x[col]
  } else { t.v0 = 0.0f; t.v1 = 0.0f; t.wc = 0.0f; }
  return t;
}

// Shuffle-combine: lh = sum x[col-7..col], rh = sum x[col..col+7], w = x[col]
__device__ __forceinline__ void row_combine(const RowLd& t, int lane,
                                            float& lh, float& rh, float& w) {
  float lf = fwd8(t.v0);
  float lb = bwd8(t.wc);
  bool lo = (lane <= 56);
  lh = lo ? lf : lb;
  float rsh = __shfl_down(lh, 7, 64);   // rh[col] = lh[col+7], bitwise == fwd8(wc)
  float rb  = bwd8(t.v1);
  rh = lo ? rsh : rb;
  w  = t.wc;
}

// One SWF step. Wave owns a 64-col x 32-row tile; 16-deep register ring of
// (lh, rh, w) rows; vertical 8-windows maintained as sliding sums (12 ops/px
// instead of 48); global loads software-pipelined one row ahead.
__global__ __launch_bounds__(256) void swf_step(const float* __restrict__ src,
                                                float* __restrict__ dst) {
  const int lane = threadIdx.x & 63;
  const int wid  = threadIdx.x >> 6;
  const int col  = blockIdx.x * 64 + lane;             // 16 strips x 64
  const int y0   = (blockIdx.y * 4 + wid) * 32;        // 32 chunks x 32 rows
  const float* s = src + (size_t)blockIdx.z * HH * WW;
  float* d       = dst + (size_t)blockIdx.z * HH * WW;

  float rlh[16], rrh[16], rw[16];

  // Prologue: rows y0-8 .. y0+6 (15 rows) into slot row&15 = (j+8)&15.
  #pragma unroll
  for (int j = 0; j < 15; ++j) {
    const int slot = (j + 8) & 15;
    RowLd t = row_load(s, y0 - 8 + j, col);
    row_combine(t, lane, rlh[slot], rrh[slot], rw[slot]);
  }

  // Sliding-window accumulators for "previous output row" y0-1:
  //   u* over rows y0-8..y0-1 (slots 8..15), d* over rows y0-1..y0+6 (15,0..6)
  float ua = 0.f, ub = 0.f, uc = 0.f, da = 0.f, db = 0.f, dc = 0.f;
  #pragma unroll
  for (int j = 0; j < 8; ++j) {
    const int sl = (8 + j) & 15;
    ua += rlh[sl]; ub += rrh[sl]; uc += rw[sl];
  }
  #pragma unroll
  for (int j = 0; j < 8; ++j) {
    const int sl = (15 + j) & 15;
    da += rlh[sl]; db += rrh[sl]; dc += rw[sl];
  }

  RowLd tmp[2];
  tmp[0] = row_load(s, y0 + 7, col);   // prime the pipeline

  #pragma unroll 1
  for (int yb = 0; yb < 32; yb += 16) {
    #pragma unroll
    for (int i = 0; i < 16; ++i) {
      const int y = y0 + yb + i;
      // prefetch row y+8 (consumed next iteration); static index after unroll
      tmp[(i + 1) & 1] = row_load(s, y + 8, col);
      // combine row y+7 into ring (evicts row y-9, last used at iter i-1)
      const int ls = (i + 7) & 15;
      row_combine(tmp[i & 1], lane, rlh[ls], rrh[ls], rw[ls]);

      // slide windows from row y-1 to row y
      ua += rlh[i];  ua -= rlh[(i + 8) & 15];
      ub += rrh[i];  ub -= rrh[(i + 8) & 15];
      uc += rw [i];  uc -= rw [(i + 8) & 15];
      da += rlh[ls]; da -= rlh[(i + 15) & 15];
      db += rrh[ls]; db -= rrh[(i + 15) & 15];
      dc += rw [ls]; dc -= rw [(i + 15) & 15];

      const float lh0 = rlh[i], rh0 = rrh[i], w0 = rw[i];
      const float ih = 1.0f / 120.0f, iq = 1.0f / 64.0f;
      const float nw0 = -w0;
      const float Ls = ua + da - lh0;   // full 15 rows, left cols
      const float Rs = ub + db - rh0;
      const float Us = ua + ub - uc;    // up 8 rows, full 15 cols
      const float Ds = da + db - dc;
      float d0 = fmaf(Ls, ih, nw0);   // L
      float d1 = fmaf(Rs, ih, nw0);   // R
      float d2 = fmaf(Us, ih, nw0);   // U
      float d3 = fmaf(Ds, ih, nw0);   // D
      float d4 = fmaf(ua, iq, nw0);   // NW
      float d5 = fmaf(ub, iq, nw0);   // NE
      float d6 = fmaf(da, iq, nw0);   // SW
      float d7 = fmaf(db, iq, nw0);   // SE

      // argmin over |d|, first index wins (strict <), matching jnp.argmin
      float bd = d0, ba = fabsf(d0);
      { float a1 = fabsf(d1); if (a1 < ba) { ba = a1; bd = d1; } }
      { float a1 = fabsf(d2); if (a1 < ba) { ba = a1; bd = d2; } }
      { float a1 = fabsf(d3); if (a1 < ba) { ba = a1; bd = d3; } }
      { float a1 = fabsf(d4); if (a1 < ba) { ba = a1; bd = d4; } }
      { float a1 = fabsf(d5); if (a1 < ba) { ba = a1; bd = d5; } }
      { float a1 = fabsf(d6); if (a1 < ba) { ba = a1; bd = d6; } }
      { float a1 = fabsf(d7); if (a1 < ba) { ba = a1; bd = d7; } }

      d[(size_t)y * WW + col] = w0 + bd;
    }
  }
}

extern "C" void kernel_launch(void* const* d_in, const int* in_sizes, int n_in,
                              void* d_out, int out_size, void* d_ws, size_t ws_size,
                              hipStream_t stream) {
  const float* in = (const float*)d_in[0];
  float* out = (float*)d_out;
  float* ws  = (float*)d_ws;   // needs 12*1024*1024*4 = 50.3 MB scratch

  dim3 grid(WW / 64, 8, NIMG);  // 16 col-strips, 8 chunk-groups (x4 waves x 32 rows), 12 planes
  dim3 block(256);

  // iteration = 3 (from setup_inputs), radius = 7 baked in.
  swf_step<<<grid, block, 0, stream>>>(in, out);   // step 1: in  -> out
  swf_step<<<grid, block, 0, stream>>>(out, ws);   // step 2: out -> ws
  swf_step<<<grid, block, 0, stream>>>(ws, out);   // step 3: ws  -> out
}

// Round 7
// 138.365 us; speedup vs baseline: 1.3898x; 1.1123x over previous
//
#include <hip/hip_runtime.h>

#define HH 1024
#define WW 1024
#define NIMG 12

// fwd8: F(l) = sum of a over lanes l..l+7   (valid for lane <= 56)
__device__ __forceinline__ float fwd8(float a) {
  a += __shfl_down(a, 1, 64);
  a += __shfl_down(a, 2, 64);
  a += __shfl_down(a, 4, 64);
  return a;
}
// bwd8: B(l) = sum of a over lanes l-7..l (valid for lane >= 7); same balanced
// pairwise tree as fwd8 over the same 8 values -> bitwise-identical result.
__device__ __forceinline__ float bwd8(float a) {
  a += __shfl_up(a, 1, 64);
  a += __shfl_up(a, 2, 64);
  a += __shfl_up(a, 4, 64);
  return a;
}

struct RowLd { float v0, v1, wc; };

// Issue the 3 global loads for row ry (zero padded outside image).
__device__ __forceinline__ RowLd row_load(const float* __restrict__ s, int ry, int col) {
  RowLd t;
  if ((unsigned)ry < (unsigned)HH) {
    const float* r = s + (size_t)ry * WW;
    t.v0 = (col >= 7) ? r[col - 7] : 0.0f;      // x[col-7]
    t.v1 = (col + 7 < WW) ? r[col + 7] : 0.0f;  // x[col+7]
    t.wc = r[col];                              // x[col]
  } else { t.v0 = 0.0f; t.v1 = 0.0f; t.wc = 0.0f; }
  return t;
}

// Shuffle-combine: lh = sum x[col-7..col], rh = sum x[col..col+7], w = x[col]
__device__ __forceinline__ void row_combine(const RowLd& t, int lane,
                                            float& lh, float& rh, float& w) {
  float lf = fwd8(t.v0);
  float lb = bwd8(t.wc);
  bool lo = (lane <= 56);
  lh = lo ? lf : lb;
  float rsh = __shfl_down(lh, 7, 64);   // rh[col] = lh[col+7], bitwise == fwd8(wc)
  float rb  = bwd8(t.v1);
  rh = lo ? rsh : rb;
  w  = t.wc;
}

// One SWF step. Wave owns a 64-col x 32-row tile; 16-deep register ring of
// (lh, rh, w) rows; vertical 8-windows as sliding sums; global loads
// software-pipelined THREE rows ahead (tmp[4] ring) to cover ~900cy HBM latency.
__global__ __launch_bounds__(256) void swf_step(const float* __restrict__ src,
                                                float* __restrict__ dst) {
  const int lane = threadIdx.x & 63;
  const int wid  = threadIdx.x >> 6;
  const int col  = blockIdx.x * 64 + lane;             // 16 strips x 64
  const int y0   = (blockIdx.y * 4 + wid) * 32;        // 32 chunks x 32 rows
  const float* s = src + (size_t)blockIdx.z * HH * WW;
  float* d       = dst + (size_t)blockIdx.z * HH * WW;

  float rlh[16], rrh[16], rw[16];

  // Prologue: rows y0-8 .. y0+6 (15 rows) into slot row&15 = (j+8)&15.
  #pragma unroll
  for (int j = 0; j < 15; ++j) {
    const int slot = (j + 8) & 15;
    RowLd t = row_load(s, y0 - 8 + j, col);
    row_combine(t, lane, rlh[slot], rrh[slot], rw[slot]);
  }

  // Sliding-window accumulators for "previous output row" y0-1:
  //   u* over rows y0-8..y0-1 (slots 8..15), d* over rows y0-1..y0+6 (15,0..6)
  float ua = 0.f, ub = 0.f, uc = 0.f, da = 0.f, db = 0.f, dc = 0.f;
  #pragma unroll
  for (int j = 0; j < 8; ++j) {
    const int sl = (8 + j) & 15;
    ua += rlh[sl]; ub += rrh[sl]; uc += rw[sl];
  }
  #pragma unroll
  for (int j = 0; j < 8; ++j) {
    const int sl = (15 + j) & 15;
    da += rlh[sl]; db += rrh[sl]; dc += rw[sl];
  }

  // Prime the load pipeline: rows y0+7, y0+8, y0+9 (consumed at i=0,1,2).
  RowLd tmp[4];
  #pragma unroll
  for (int k = 0; k < 3; ++k) tmp[k] = row_load(s, y0 + 7 + k, col);

  #pragma unroll 1
  for (int yb = 0; yb < 32; yb += 16) {
    #pragma unroll
    for (int i = 0; i < 16; ++i) {
      const int y = y0 + yb + i;
      // prefetch row y+10 (consumed 3 iterations later); static index under unroll
      tmp[(i + 3) & 3] = row_load(s, y + 10, col);
      // combine row y+7 into ring (evicts row y-9, last used at iter i-1)
      const int ls = (i + 7) & 15;
      row_combine(tmp[i & 3], lane, rlh[ls], rrh[ls], rw[ls]);

      // slide windows from row y-1 to row y
      ua += rlh[i];  ua -= rlh[(i + 8) & 15];
      ub += rrh[i];  ub -= rrh[(i + 8) & 15];
      uc += rw [i];  uc -= rw [(i + 8) & 15];
      da += rlh[ls]; da -= rlh[(i + 15) & 15];
      db += rrh[ls]; db -= rrh[(i + 15) & 15];
      dc += rw [ls]; dc -= rw [(i + 15) & 15];

      const float lh0 = rlh[i], rh0 = rrh[i], w0 = rw[i];
      const float ih = 1.0f / 120.0f, iq = 1.0f / 64.0f;
      const float nw0 = -w0;
      const float Ls = ua + da - lh0;   // full 15 rows, left cols
      const float Rs = ub + db - rh0;
      const float Us = ua + ub - uc;    // up 8 rows, full 15 cols
      const float Ds = da + db - dc;
      float d0 = fmaf(Ls, ih, nw0);   // L
      float d1 = fmaf(Rs, ih, nw0);   // R
      float d2 = fmaf(Us, ih, nw0);   // U
      float d3 = fmaf(Ds, ih, nw0);   // D
      float d4 = fmaf(ua, iq, nw0);   // NW
      float d5 = fmaf(ub, iq, nw0);   // NE
      float d6 = fmaf(da, iq, nw0);   // SW
      float d7 = fmaf(db, iq, nw0);   // SE

      // argmin over |d|, first index wins (strict <), matching jnp.argmin
      float bd = d0, ba = fabsf(d0);
      { float a1 = fabsf(d1); if (a1 < ba) { ba = a1; bd = d1; } }
      { float a1 = fabsf(d2); if (a1 < ba) { ba = a1; bd = d2; } }
      { float a1 = fabsf(d3); if (a1 < ba) { ba = a1; bd = d3; } }
      { float a1 = fabsf(d4); if (a1 < ba) { ba = a1; bd = d4; } }
      { float a1 = fabsf(d5); if (a1 < ba) { ba = a1; bd = d5; } }
      { float a1 = fabsf(d6); if (a1 < ba) { ba = a1; bd = d6; } }
      { float a1 = fabsf(d7); if (a1 < ba) { ba = a1; bd = d7; } }

      d[(size_t)y * WW + col] = w0 + bd;
    }
  }
}

extern "C" void kernel_launch(void* const* d_in, const int* in_sizes, int n_in,
                              void* d_out, int out_size, void* d_ws, size_t ws_size,
                              hipStream_t stream) {
  const float* in = (const float*)d_in[0];
  float* out = (float*)d_out;
  float* ws  = (float*)d_ws;   // needs 12*1024*1024*4 = 50.3 MB scratch

  dim3 grid(WW / 64, 8, NIMG);  // 16 col-strips, 8 chunk-groups (x4 waves x 32 rows), 12 planes
  dim3 block(256);

  // iteration = 3 (from setup_inputs), radius = 7 baked in.
  swf_step<<<grid, block, 0, stream>>>(in, out);   // step 1: in  -> out
  swf_step<<<grid, block, 0, stream>>>(out, ws);   // step 2: out -> ws
  swf_step<<<grid, block, 0, stream>>>(ws, out);   // step 3: ws  -> out
}